// Round 4
// baseline (261.418 us; speedup 1.0000x reference)
//
#include <hip/hip_runtime.h>
#include <math.h>

constexpr int BB = 2;
constexpr int SS = 2048;
constexpr int EE = 1024;
constexpr int HH = 16;
constexpr int DD = 64;

typedef short short8 __attribute__((ext_vector_type(8)));
typedef short short4_t __attribute__((ext_vector_type(4)));
typedef float floatx4 __attribute__((ext_vector_type(4)));
typedef unsigned short ushort_t;

__device__ __forceinline__ ushort_t f2bf(float f) {
    unsigned int u = __float_as_uint(f);
    u += 0x7fffu + ((u >> 16) & 1u);   // RNE
    return (ushort_t)(u >> 16);
}
__device__ __forceinline__ float bf2f(short s) {
    return __uint_as_float(((unsigned)(ushort_t)s) << 16);
}

// RNE f32x4 -> bf16x4 via v_cvt_pk_bf16_f32 (2 insts vs ~8+ for bit-math)
__device__ __forceinline__ short4_t pack_bf16x4(float a, float b, float c, float d) {
    union { unsigned u[2]; short4_t s; } r;
    asm("v_cvt_pk_bf16_f32 %0, %1, %2" : "=v"(r.u[0]) : "v"(a), "v"(b));
    asm("v_cvt_pk_bf16_f32 %0, %1, %2" : "=v"(r.u[1]) : "v"(c), "v"(d));
    return r.s;
}

// async global->LDS, 16 B per lane; LDS dest = wave-uniform base + lane*16
__device__ __forceinline__ void gl_lds16(const void* g, void* l) {
    __builtin_amdgcn_global_load_lds(
        (const __attribute__((address_space(1))) void*)g,
        (__attribute__((address_space(3))) void*)l, 16, 0, 0);
}

// ---------------------------------------------------------------------------
// fp32 -> bf16 repack with XOR-group swizzle (phys group = g ^ (row&7) within
// each 64-col block). All 3 X inputs and all 3 W matrices in one grid.
// [verbatim — passed]
// ---------------------------------------------------------------------------
__global__ __launch_bounds__(256) void repack_all(
    const float* __restrict__ x0, const float* __restrict__ x1, const float* __restrict__ x2,
    const float* __restrict__ w0, const float* __restrict__ w1, const float* __restrict__ w2,
    ushort_t* __restrict__ Xbf, ushort_t* __restrict__ Wbf)
{
    const int idx = blockIdx.x * 256 + threadIdx.x;   // group-of-8 id
    const int row = idx >> 7;                          // 128 groups per row
    const int gir = idx & 127;
    const float* src;
    ushort_t* dst;
    int r;
    if (row < 3 * BB * SS) {
        const int z = row >> 12; r = row & (BB * SS - 1);
        src = (z == 0) ? x0 : (z == 1) ? x1 : x2;
        dst = Xbf + (size_t)z * BB * SS * EE;
    } else {
        const int rw = row - 3 * BB * SS;
        const int z = rw >> 10; r = rw & (EE - 1);
        src = (z == 0) ? w0 : (z == 1) ? w1 : w2;
        dst = Wbf + (size_t)z * EE * EE;
    }
    const int blk = gir >> 3, g = gir & 7;
    const int gp = g ^ (r & 7);
    const float* sp = src + (size_t)r * EE + gir * 8;
    float4 a = *(const float4*)sp;
    float4 b = *(const float4*)(sp + 4);
    short8 o;
    o[0] = (short)f2bf(a.x); o[1] = (short)f2bf(a.y); o[2] = (short)f2bf(a.z); o[3] = (short)f2bf(a.w);
    o[4] = (short)f2bf(b.x); o[5] = (short)f2bf(b.y); o[6] = (short)f2bf(b.z); o[7] = (short)f2bf(b.w);
    *(short8*)&dst[(size_t)r * EE + blk * 64 + gp * 8] = o;
}

// ---------------------------------------------------------------------------
// bf16 projection GEMM: 128x128 tile, BK=64, global_load_lds staging.
// z=0/1: q/k -> [bh][s][d] bf16 swizzled;  z=2: vt -> [bh][d][s] bf16 swizzled
// [verbatim — passed]
// ---------------------------------------------------------------------------
__global__ __launch_bounds__(256) void proj_kernel(
    const ushort_t* __restrict__ Xall, const ushort_t* __restrict__ Wall,
    const float* __restrict__ bq, const float* __restrict__ bk, const float* __restrict__ bv,
    ushort_t* __restrict__ qb, ushort_t* __restrict__ kbb, ushort_t* __restrict__ vtb)
{
    __shared__ __align__(16) ushort_t Xs[128 * 64];
    __shared__ __align__(16) ushort_t Ws[128 * 64];

    const int z = blockIdx.z;
    const ushort_t* X = Xall + (size_t)z * BB * SS * EE;
    const ushort_t* W = Wall + (size_t)z * EE * EE;
    const float* bias = (z == 0) ? bq : (z == 1) ? bk : bv;

    const int t = threadIdx.x, w = t >> 6, l = t & 63, ln = t & 15, qd = (t >> 4) & 3;
    const int row0 = blockIdx.x * 128;
    const int col0 = blockIdx.y * 128;
    const int wzm = (w & 1) * 64, wzn = (w >> 1) * 64;

    floatx4 acc[4][4];
    #pragma unroll
    for (int i = 0; i < 4; ++i)
        #pragma unroll
        for (int j = 0; j < 4; ++j)
            acc[i][j] = (floatx4){0.f, 0.f, 0.f, 0.f};

    for (int k0 = 0; k0 < EE; k0 += 64) {
        __syncthreads();
        #pragma unroll
        for (int j = 0; j < 4; ++j) {
            const int c = w * 4 + j;
            const int r = c * 8 + (l >> 3);
            gl_lds16(&X[(size_t)(row0 + r) * EE + k0 + (l & 7) * 8], &Xs[c * 512]);
            gl_lds16(&W[(size_t)(col0 + r) * EE + k0 + (l & 7) * 8], &Ws[c * 512]);
        }
        __syncthreads();

        const ushort_t* Am = (z < 2) ? Ws : Xs;
        const ushort_t* Bn = (z < 2) ? Xs : Ws;
        #pragma unroll
        for (int kh = 0; kh < 2; ++kh) {
            const int sw = ((kh * 4 + qd) ^ (ln & 7)) * 8;
            short8 af[4], bfr[4];
            #pragma unroll
            for (int mi = 0; mi < 4; ++mi)
                af[mi] = *(const short8*)&Am[(wzm + mi * 16 + ln) * 64 + sw];
            #pragma unroll
            for (int ni = 0; ni < 4; ++ni)
                bfr[ni] = *(const short8*)&Bn[(wzn + ni * 16 + ln) * 64 + sw];
            #pragma unroll
            for (int mi = 0; mi < 4; ++mi)
                #pragma unroll
                for (int ni = 0; ni < 4; ++ni)
                    acc[mi][ni] = __builtin_amdgcn_mfma_f32_16x16x32_bf16(af[mi], bfr[ni], acc[mi][ni], 0, 0, 0);
        }
    }

    if (z < 2) {
        ushort_t* dst = z ? kbb : qb;
        #pragma unroll
        for (int mi = 0; mi < 4; ++mi) {
            const int o0 = col0 + wzm + mi * 16 + qd * 4;
            const float4 b4 = *(const float4*)&bias[o0];
            const int h = o0 >> 6, d0 = o0 & 63;
            const int g = d0 >> 3, dlow = d0 & 7;
            #pragma unroll
            for (int ni = 0; ni < 4; ++ni) {
                const int s = row0 + wzn + ni * 16 + ln;
                const int b = s >> 11, sr = s & (SS - 1);
                const int gp = g ^ (sr & 7);
                short4_t pk;
                pk[0] = (short)f2bf(acc[mi][ni][0] + b4.x);
                pk[1] = (short)f2bf(acc[mi][ni][1] + b4.y);
                pk[2] = (short)f2bf(acc[mi][ni][2] + b4.z);
                pk[3] = (short)f2bf(acc[mi][ni][3] + b4.w);
                *(short4_t*)&dst[((size_t)((b * HH + h) * SS) + sr) * DD + gp * 8 + dlow] = pk;
            }
        }
    } else {
        #pragma unroll
        for (int mi = 0; mi < 4; ++mi) {
            const int s0 = row0 + wzm + mi * 16 + qd * 4;
            const int b = s0 >> 11, sr0 = s0 & (SS - 1);
            const int sg = (sr0 >> 3) & 7, slow = sr0 & 7;
            #pragma unroll
            for (int ni = 0; ni < 4; ++ni) {
                const int o = col0 + wzn + ni * 16 + ln;
                const int h = o >> 6, d = o & 63;
                const float bvv = bias[o];
                const int gp2 = sg ^ (d & 7);
                short4_t pk;
                pk[0] = (short)f2bf(acc[mi][ni][0] + bvv);
                pk[1] = (short)f2bf(acc[mi][ni][1] + bvv);
                pk[2] = (short)f2bf(acc[mi][ni][2] + bvv);
                pk[3] = (short)f2bf(acc[mi][ni][3] + bvv);
                *(short4_t*)&vtb[((size_t)((b * HH + h) * DD) + d) * SS + (sr0 & ~63) + gp2 * 8 + slow] = pk;
            }
        }
    }
}

// ---------------------------------------------------------------------------
// 64-s chunk SUFFIX sums of V from bf16 vt[bh][d][s]  [verbatim — passed]
// ---------------------------------------------------------------------------
__global__ __launch_bounds__(256) void scan_chunks(
    const ushort_t* __restrict__ vtb, float* __restrict__ segsuf)
{
    const int t = threadIdx.x;
    const int d = blockIdx.x * 8 + (t >> 5);
    const int ch = t & 31;
    const int bh = blockIdx.y;
    const ushort_t* src = vtb + ((size_t)(bh * DD + d)) * SS + ch * 64;
    float s = 0.f;
    #pragma unroll
    for (int i = 0; i < 8; ++i) {
        short8 v = *(const short8*)&src[i * 8];
        #pragma unroll
        for (int j = 0; j < 8; ++j) s += bf2f(v[j]);
    }
    #pragma unroll
    for (int delta = 1; delta < 32; delta <<= 1) {
        const float v = __shfl_down(s, delta, 32);
        if (ch + delta < 32) s += v;
    }
    segsuf[((size_t)bh * 33 + ch) * 64 + d] = s;
    if (ch == 31) segsuf[((size_t)bh * 33 + 32) * 64 + d] = 0.f;
}

// ---------------------------------------------------------------------------
// MFMA causal attention, log-softmax decomposition, P kept in registers.
// R9 = R7 structure (16 q-rows/wave, passed at 53.7us, 52 VGPR) +
//  (1) UNIFORM WORK: each block runs q-tile pair (31-p, p) sequentially ->
//      every block = exactly 33 k-tile iterations (R7's tail imbalance was
//      the occupancy hole: trips {32-t,24-t,9+t,1+t} per CU, no backfill).
//      Grid 512 x 256thr (2 blocks/CU steady, zero tail).
//  (2) pos_bias read from GLOBAL (L1-resident 8KB table) not LDS: removes
//      16 LDS-pipe ops/tile from the busiest pipe; LDS 40KB -> 32KB.
//      vmcnt ledger stays valid (pb loads are older than staging loads).
//  (3) v_cvt_pk_bf16_f32 packing (saves ~56 VALU insts/tile).
//  (4) s_setprio(1) around MFMA clusters (m191: attn-positive).
// R8 post-mortem honored: NO doubling of accumulator state (WRITE_SIZE
// showed 13.8MB of spill traffic there).
// ---------------------------------------------------------------------------
__global__ __launch_bounds__(256, 4) void attn_kernel(
    const ushort_t* __restrict__ qb, const ushort_t* __restrict__ kbb,
    const ushort_t* __restrict__ vtb, const float* __restrict__ segsuf,
    const float* __restrict__ pb, float* __restrict__ out)
{
    __shared__ __align__(16) ushort_t Ks[2][64 * 64];   // [k][d], swizzled by k&7
    __shared__ __align__(16) ushort_t Vt[2][64 * 64];   // [d][k], swizzled by d&7

    const int t = threadIdx.x, w = t >> 6, ln = t & 15, qd = (t >> 4) & 3;

    const int id = blockIdx.x;
    const int bh = id & 31, p_ = id >> 5;             // p_ in 0..15
    const int b = bh >> 4, h = bh & 15;
    const int qtA = 31 - p_, nA = qtA + 1;            // heavy phase first
    const int qtB = p_;                                // nA + nB = 33 uniform
    const int r0 = 16 * w;                            // wave's q-row offset

    const ushort_t* Kbh = kbb + (size_t)bh * SS * DD;
    const ushort_t* Vbh = vtb + (size_t)bh * DD * SS;
    const float* pbh = pb + h * (2 * SS - 1) + (SS - 1);   // pbh[rel], rel>=0

    // cooperative stage of one 64x64 K tile + one 64x64 Vt tile (4 loads/thr)
    const int srow = t >> 3, scg = t & 7;             // 32 rows x 8 groups
    auto stageg = [&](int buf, int g) {
        const int k0 = ((g < nA) ? g : (g - nA)) * 64;
        gl_lds16(&Kbh[(size_t)(k0 + srow) * DD + scg * 8],      &Ks[buf][w * 512]);
        gl_lds16(&Kbh[(size_t)(k0 + 32 + srow) * DD + scg * 8], &Ks[buf][2048 + w * 512]);
        gl_lds16(&Vbh[(size_t)srow * SS + k0 + scg * 8],        &Vt[buf][w * 512]);
        gl_lds16(&Vbh[(size_t)(32 + srow) * SS + k0 + scg * 8], &Vt[buf][2048 + w * 512]);
    };

    // Q fragments (B-operand of St): q-row = qt*64 + r0 + ln
    short8 qf[2];
    auto loadQ = [&](int qt) {
        #pragma unroll
        for (int kh = 0; kh < 2; ++kh)
            qf[kh] = *(const short8*)&qb[((size_t)bh * SS + qt * 64 + r0 + ln) * DD + (((kh * 4 + qd) ^ (ln & 7)) * 8)];
    };

    floatx4 accpv[4], accsv[4];
    float psum0, psum1;
    auto resetAcc = [&]() {
        #pragma unroll
        for (int ct = 0; ct < 4; ++ct) {
            accpv[ct] = (floatx4){0.f, 0.f, 0.f, 0.f};
            accsv[ct] = (floatx4){0.f, 0.f, 0.f, 0.f};
        }
        psum0 = 0.f; psum1 = 0.f;
    };

    // per-phase epilogue: lse reduce + suffix-table reads + out writes
    auto epilogue = [&](int qt) {
        float p = psum0 + psum1;
        p += __shfl_xor(p, 16, 64);
        p += __shfl_xor(p, 32, 64);
        const float lseq = __logf(p);            // lse for q-row = ln
        float lseR[4];
        #pragma unroll
        for (int reg = 0; reg < 4; ++reg)
            lseR[reg] = __shfl(lseq, qd * 4 + reg, 64);   // C-layout row
        const int cmin = qt + 1;
        float tot[4], tail[4];
        #pragma unroll
        for (int ct = 0; ct < 4; ++ct) {
            const int d = ct * 16 + ln;
            tot[ct]  = segsuf[((size_t)bh * 33) * 64 + d];
            tail[ct] = segsuf[((size_t)bh * 33 + cmin) * 64 + d];
        }
        const int i0 = qt * 64;
        #pragma unroll
        for (int ct = 0; ct < 4; ++ct) {
            const int d = ct * 16 + ln;
            #pragma unroll
            for (int reg = 0; reg < 4; ++reg) {
                const int ig = i0 + r0 + qd * 4 + reg;
                const float o = accpv[ct][reg] - lseR[reg] * tot[ct]
                              - 1e9f * (accsv[ct][reg] + tail[ct]);
                out[((size_t)(b * SS + ig)) * EE + h * DD + d] = o;
            }
        }
    };

    loadQ(qtA);
    resetAcc();
    stageg(0, 0);
    __syncthreads();              // one-time full drain: qf + tile 0

    int qt = qtA, kbase = 0;      // current phase tile index base
    for (int g = 0; g < 33; ++g) {
        if (g + 1 < 33) {
            stageg((g + 1) & 1, g + 1);           // next tile in flight
            asm volatile("s_waitcnt vmcnt(4)" ::: "memory");   // cur tile done
        } else {
            asm volatile("s_waitcnt vmcnt(0)" ::: "memory");
        }
        __builtin_amdgcn_s_barrier();             // everyone's cur tile done

        const int kt = g - kbase;
        const int k0 = kt * 64;
        const bool diag = (kt == qt);             // block-uniform
        const int i0 = qt * 64;
        const ushort_t* KsC = Ks[g & 1];
        const ushort_t* VtC = Vt[g & 1];

        // St = K·Q^T: A = K rows (m=k), B = Q rows (n=q). 4 m-tiles x 2 kh.
        floatx4 aq[4];
        #pragma unroll
        for (int mt = 0; mt < 4; ++mt) aq[mt] = (floatx4){0.f, 0.f, 0.f, 0.f};
        __builtin_amdgcn_s_setprio(1);
        #pragma unroll
        for (int kh = 0; kh < 2; ++kh) {
            const int sw = ((kh * 4 + qd) ^ (ln & 7)) * 8;
            #pragma unroll
            for (int mt = 0; mt < 4; ++mt) {
                short8 af = *(const short8*)&KsC[(mt * 16 + ln) * 64 + sw];
                aq[mt] = __builtin_amdgcn_mfma_f32_16x16x32_bf16(af, qf[kh], aq[mt], 0, 0, 0);
            }
        }
        __builtin_amdgcn_s_setprio(0);

        // softmax terms in registers; lane holds q = ln, k = k0+mt*16+qd*4+reg
        short4_t pfrag[4];
        if (!diag) {
            const int base0 = i0 - k0 + r0 + ln;  // >= 64: never masked
            #pragma unroll
            for (int mt = 0; mt < 4; ++mt) {
                const int base = base0 - mt * 16 - qd * 4;
                const float v0 = aq[mt][0] * 0.125f + pbh[base];
                const float v1 = aq[mt][1] * 0.125f + pbh[base - 1];
                const float v2 = aq[mt][2] * 0.125f + pbh[base - 2];
                const float v3 = aq[mt][3] * 0.125f + pbh[base - 3];
                psum0 += __expf(v0) + __expf(v2);
                psum1 += __expf(v1) + __expf(v3);
                pfrag[mt] = pack_bf16x4(v0, v1, v2, v3);
            }
        } else {
            #pragma unroll
            for (int mt = 0; mt < 4; ++mt) {
                const int base = r0 + ln - mt * 16 - qd * 4;   // i0-k0 == 0
                float vv[4];
                #pragma unroll
                for (int reg = 0; reg < 4; ++reg) {
                    const int rel = base - reg;
                    const bool ok = rel >= 0;
                    const float val = aq[mt][reg] * 0.125f + pbh[ok ? rel : 0];
                    vv[reg] = ok ? val : 0.f;
                    psum0 += ok ? __expf(val) : 0.f;
                }
                pfrag[mt] = pack_bf16x4(vv[0], vv[1], vv[2], vv[3]);
            }
        }

        // PV (and U·V for Sv on the diagonal tile)
        const int iloc = r0 + ln;
        __builtin_amdgcn_s_setprio(1);
        #pragma unroll
        for (int kk = 0; kk < 4; ++kk) {
            short4_t uf;
            if (diag) {
                #pragma unroll
                for (int j = 0; j < 4; ++j)
                    uf[j] = (kk * 16 + qd * 4 + j > iloc) ? (short)0x3F80 : (short)0;
            }
            #pragma unroll
            for (int ct = 0; ct < 4; ++ct) {
                const int off = (ct * 16 + ln) * 64 + (((kk * 2 + (qd >> 1)) ^ (ln & 7)) * 8 + (qd & 1) * 4);
                short4_t bfr = *(const short4_t*)&VtC[off];
                accpv[ct] = __builtin_amdgcn_mfma_f32_16x16x16bf16_1k(pfrag[kk], bfr, accpv[ct], 0, 0, 0);
                if (diag)
                    accsv[ct] = __builtin_amdgcn_mfma_f32_16x16x16bf16_1k(uf, bfr, accsv[ct], 0, 0, 0);
            }
        }
        __builtin_amdgcn_s_setprio(0);

        if (g + 1 < 33)
            __builtin_amdgcn_s_barrier();         // all reads of cur done

        if (diag) {                               // end of phase: flush & swap
            epilogue(qt);
            if (g + 1 < 33) {                     // switch to light phase B
                loadQ(qtB);
                resetAcc();
                qt = qtB; kbase = nA;
            }
        }
    }
}

// ---------------------------------------------------------------------------
extern "C" void kernel_launch(void* const* d_in, const int* in_sizes, int n_in,
                              void* d_out, int out_size, void* d_ws, size_t ws_size,
                              hipStream_t stream)
{
    const float* query = (const float*)d_in[0];
    const float* key_  = (const float*)d_in[1];
    const float* value = (const float*)d_in[2];
    const float* Wq = (const float*)d_in[3];
    const float* bq = (const float*)d_in[4];
    const float* Wk = (const float*)d_in[5];
    const float* bk = (const float*)d_in[6];
    const float* Wv = (const float*)d_in[7];
    const float* bv = (const float*)d_in[8];
    const float* pb = (const float*)d_in[9];
    float* out = (float*)d_out;

    float* ws = (float*)d_ws;
    const size_t SZ = (size_t)BB * SS * EE;          // 4M elements
    float* segsuf = ws;                               // 32 bh x 33 c x 64 d
    ushort_t* us  = (ushort_t*)(segsuf + (size_t)BB * HH * 33 * DD);
    ushort_t* qbp = us;                               // bf16 q  [bh][s][d] swz
    ushort_t* kbp = qbp + SZ;                         // bf16 k  [bh][s][d] swz
    ushort_t* vtp = kbp + SZ;                         // bf16 vt [bh][d][s] swz
    ushort_t* Xbf = vtp + SZ;                         // 3 x (B*S x E)
    ushort_t* Wbf = Xbf + 3 * SZ;                     // 3 x (E x E)

    const int ngroups = (3 * BB * SS + 3 * EE) * (EE / 8);
    repack_all<<<ngroups / 256, 256, 0, stream>>>(query, key_, value, Wq, Wk, Wv, Xbf, Wbf);

    proj_kernel<<<dim3(BB * SS / 128, EE / 128, 3), 256, 0, stream>>>(
        Xbf, Wbf, bq, bk, bv, qbp, kbp, vtp);

    scan_chunks<<<dim3(8, BB * HH), 256, 0, stream>>>(vtp, segsuf);

    attn_kernel<<<BB * HH * 16, 256, 0, stream>>>(
        qbp, kbp, vtp, segsuf, pb, out);
}

// Round 5
// 225.235 us; speedup vs baseline: 1.1606x; 1.1606x over previous
//
#include <hip/hip_runtime.h>
#include <math.h>

constexpr int BB = 2;
constexpr int SS = 2048;
constexpr int EE = 1024;
constexpr int HH = 16;
constexpr int DD = 64;

typedef short short8 __attribute__((ext_vector_type(8)));
typedef short short4_t __attribute__((ext_vector_type(4)));
typedef float floatx4 __attribute__((ext_vector_type(4)));
typedef unsigned short ushort_t;

__device__ __forceinline__ ushort_t f2bf(float f) {
    unsigned int u = __float_as_uint(f);
    u += 0x7fffu + ((u >> 16) & 1u);   // RNE
    return (ushort_t)(u >> 16);
}
__device__ __forceinline__ float bf2f(short s) {
    return __uint_as_float(((unsigned)(ushort_t)s) << 16);
}

// RNE f32x4 -> bf16x4 via v_cvt_pk_bf16_f32 (bit-identical to f2bf, ~6x fewer
// VALU insts). Validated numerically in R8/R9 (both passed).
__device__ __forceinline__ short4_t pack_bf16x4(float a, float b, float c, float d) {
    union { unsigned u[2]; short4_t s; } r;
    asm("v_cvt_pk_bf16_f32 %0, %1, %2" : "=v"(r.u[0]) : "v"(a), "v"(b));
    asm("v_cvt_pk_bf16_f32 %0, %1, %2" : "=v"(r.u[1]) : "v"(c), "v"(d));
    return r.s;
}

// async global->LDS, 16 B per lane; LDS dest = wave-uniform base + lane*16
__device__ __forceinline__ void gl_lds16(const void* g, void* l) {
    __builtin_amdgcn_global_load_lds(
        (const __attribute__((address_space(1))) void*)g,
        (__attribute__((address_space(3))) void*)l, 16, 0, 0);
}

// ---------------------------------------------------------------------------
// fp32 -> bf16 repack with XOR-group swizzle (phys group = g ^ (row&7) within
// each 64-col block). All 3 X inputs and all 3 W matrices in one grid.
// [R4 structure; f2bf chain -> v_cvt_pk_bf16_f32, bit-identical]
// ---------------------------------------------------------------------------
__global__ __launch_bounds__(256) void repack_all(
    const float* __restrict__ x0, const float* __restrict__ x1, const float* __restrict__ x2,
    const float* __restrict__ w0, const float* __restrict__ w1, const float* __restrict__ w2,
    ushort_t* __restrict__ Xbf, ushort_t* __restrict__ Wbf)
{
    const int idx = blockIdx.x * 256 + threadIdx.x;   // group-of-8 id
    const int row = idx >> 7;                          // 128 groups per row
    const int gir = idx & 127;
    const float* src;
    ushort_t* dst;
    int r;
    if (row < 3 * BB * SS) {
        const int z = row >> 12; r = row & (BB * SS - 1);
        src = (z == 0) ? x0 : (z == 1) ? x1 : x2;
        dst = Xbf + (size_t)z * BB * SS * EE;
    } else {
        const int rw = row - 3 * BB * SS;
        const int z = rw >> 10; r = rw & (EE - 1);
        src = (z == 0) ? w0 : (z == 1) ? w1 : w2;
        dst = Wbf + (size_t)z * EE * EE;
    }
    const int blk = gir >> 3, g = gir & 7;
    const int gp = g ^ (r & 7);
    const float* sp = src + (size_t)r * EE + gir * 8;
    float4 a = *(const float4*)sp;
    float4 b = *(const float4*)(sp + 4);
    union { unsigned u[4]; short8 s; } o;
    asm("v_cvt_pk_bf16_f32 %0, %1, %2" : "=v"(o.u[0]) : "v"(a.x), "v"(a.y));
    asm("v_cvt_pk_bf16_f32 %0, %1, %2" : "=v"(o.u[1]) : "v"(a.z), "v"(a.w));
    asm("v_cvt_pk_bf16_f32 %0, %1, %2" : "=v"(o.u[2]) : "v"(b.x), "v"(b.y));
    asm("v_cvt_pk_bf16_f32 %0, %1, %2" : "=v"(o.u[3]) : "v"(b.z), "v"(b.w));
    *(short8*)&dst[(size_t)r * EE + blk * 64 + gp * 8] = o.s;
}

// ---------------------------------------------------------------------------
// bf16 projection GEMM: 128x128 tile, BK=64, global_load_lds staging.
// z=0/1: q/k -> [bh][s][d] bf16 swizzled;  z=2: vt -> [bh][d][s] bf16 swizzled
// [R4 structure; epilogue f2bf -> cvt_pk, bit-identical]
// ---------------------------------------------------------------------------
__global__ __launch_bounds__(256) void proj_kernel(
    const ushort_t* __restrict__ Xall, const ushort_t* __restrict__ Wall,
    const float* __restrict__ bq, const float* __restrict__ bk, const float* __restrict__ bv,
    ushort_t* __restrict__ qb, ushort_t* __restrict__ kbb, ushort_t* __restrict__ vtb)
{
    __shared__ __align__(16) ushort_t Xs[128 * 64];
    __shared__ __align__(16) ushort_t Ws[128 * 64];

    const int z = blockIdx.z;
    const ushort_t* X = Xall + (size_t)z * BB * SS * EE;
    const ushort_t* W = Wall + (size_t)z * EE * EE;
    const float* bias = (z == 0) ? bq : (z == 1) ? bk : bv;

    const int t = threadIdx.x, w = t >> 6, l = t & 63, ln = t & 15, qd = (t >> 4) & 3;
    const int row0 = blockIdx.x * 128;
    const int col0 = blockIdx.y * 128;
    const int wzm = (w & 1) * 64, wzn = (w >> 1) * 64;

    floatx4 acc[4][4];
    #pragma unroll
    for (int i = 0; i < 4; ++i)
        #pragma unroll
        for (int j = 0; j < 4; ++j)
            acc[i][j] = (floatx4){0.f, 0.f, 0.f, 0.f};

    for (int k0 = 0; k0 < EE; k0 += 64) {
        __syncthreads();
        #pragma unroll
        for (int j = 0; j < 4; ++j) {
            const int c = w * 4 + j;
            const int r = c * 8 + (l >> 3);
            gl_lds16(&X[(size_t)(row0 + r) * EE + k0 + (l & 7) * 8], &Xs[c * 512]);
            gl_lds16(&W[(size_t)(col0 + r) * EE + k0 + (l & 7) * 8], &Ws[c * 512]);
        }
        __syncthreads();

        const ushort_t* Am = (z < 2) ? Ws : Xs;
        const ushort_t* Bn = (z < 2) ? Xs : Ws;
        #pragma unroll
        for (int kh = 0; kh < 2; ++kh) {
            const int sw = ((kh * 4 + qd) ^ (ln & 7)) * 8;
            short8 af[4], bfr[4];
            #pragma unroll
            for (int mi = 0; mi < 4; ++mi)
                af[mi] = *(const short8*)&Am[(wzm + mi * 16 + ln) * 64 + sw];
            #pragma unroll
            for (int ni = 0; ni < 4; ++ni)
                bfr[ni] = *(const short8*)&Bn[(wzn + ni * 16 + ln) * 64 + sw];
            #pragma unroll
            for (int mi = 0; mi < 4; ++mi)
                #pragma unroll
                for (int ni = 0; ni < 4; ++ni)
                    acc[mi][ni] = __builtin_amdgcn_mfma_f32_16x16x32_bf16(af[mi], bfr[ni], acc[mi][ni], 0, 0, 0);
        }
    }

    if (z < 2) {
        ushort_t* dst = z ? kbb : qb;
        #pragma unroll
        for (int mi = 0; mi < 4; ++mi) {
            const int o0 = col0 + wzm + mi * 16 + qd * 4;
            const float4 b4 = *(const float4*)&bias[o0];
            const int h = o0 >> 6, d0 = o0 & 63;
            const int g = d0 >> 3, dlow = d0 & 7;
            #pragma unroll
            for (int ni = 0; ni < 4; ++ni) {
                const int s = row0 + wzn + ni * 16 + ln;
                const int b = s >> 11, sr = s & (SS - 1);
                const int gp = g ^ (sr & 7);
                short4_t pk = pack_bf16x4(acc[mi][ni][0] + b4.x, acc[mi][ni][1] + b4.y,
                                          acc[mi][ni][2] + b4.z, acc[mi][ni][3] + b4.w);
                *(short4_t*)&dst[((size_t)((b * HH + h) * SS) + sr) * DD + gp * 8 + dlow] = pk;
            }
        }
    } else {
        #pragma unroll
        for (int mi = 0; mi < 4; ++mi) {
            const int s0 = row0 + wzm + mi * 16 + qd * 4;
            const int b = s0 >> 11, sr0 = s0 & (SS - 1);
            const int sg = (sr0 >> 3) & 7, slow = sr0 & 7;
            #pragma unroll
            for (int ni = 0; ni < 4; ++ni) {
                const int o = col0 + wzn + ni * 16 + ln;
                const int h = o >> 6, d = o & 63;
                const float bvv = bias[o];
                const int gp2 = sg ^ (d & 7);
                short4_t pk = pack_bf16x4(acc[mi][ni][0] + bvv, acc[mi][ni][1] + bvv,
                                          acc[mi][ni][2] + bvv, acc[mi][ni][3] + bvv);
                *(short4_t*)&vtb[((size_t)((b * HH + h) * DD) + d) * SS + (sr0 & ~63) + gp2 * 8 + slow] = pk;
            }
        }
    }
}

// ---------------------------------------------------------------------------
// 64-s chunk SUFFIX sums of V from bf16 vt[bh][d][s]  [verbatim — passed]
// ---------------------------------------------------------------------------
__global__ __launch_bounds__(256) void scan_chunks(
    const ushort_t* __restrict__ vtb, float* __restrict__ segsuf)
{
    const int t = threadIdx.x;
    const int d = blockIdx.x * 8 + (t >> 5);
    const int ch = t & 31;
    const int bh = blockIdx.y;
    const ushort_t* src = vtb + ((size_t)(bh * DD + d)) * SS + ch * 64;
    float s = 0.f;
    #pragma unroll
    for (int i = 0; i < 8; ++i) {
        short8 v = *(const short8*)&src[i * 8];
        #pragma unroll
        for (int j = 0; j < 8; ++j) s += bf2f(v[j]);
    }
    #pragma unroll
    for (int delta = 1; delta < 32; delta <<= 1) {
        const float v = __shfl_down(s, delta, 32);
        if (ch + delta < 32) s += v;
    }
    segsuf[((size_t)bh * 33 + ch) * 64 + d] = s;
    if (ch == 31) segsuf[((size_t)bh * 33 + 32) * 64 + d] = 0.f;
}

// ---------------------------------------------------------------------------
// MFMA causal attention, log-softmax decomposition, P kept in registers.
// R10 = R7 EXACTLY (passed, 53.7us, 52 VGPR, no scratch) with only three
// bit-identical / schedule-neutral micro-opts (each validated in R8/R9,
// whose failures were allocation/restructure, not these primitives):
//  (1) v_cvt_pk_bf16_f32 P-fragment packing (f2bf chain was ~4 insts/value)
//  (2) s_setprio(1) around the St and PV MFMA clusters (m191 attn-positive)
//  (3) psum parity split (breaks serial exp-add chain)
// NO structural change: same grid 1024, same heavy-first remap, same
// counted-vmcnt double-buffer staging, same pbL in LDS (R9 proved global
// pb reads cost +17MB HBM fetch), same 16 q-rows/wave (R8 proved 2x state
// spills at this balance point).
// ---------------------------------------------------------------------------
__global__ __launch_bounds__(256, 4) void attn_kernel(
    const ushort_t* __restrict__ qb, const ushort_t* __restrict__ kbb,
    const ushort_t* __restrict__ vtb, const float* __restrict__ segsuf,
    const float* __restrict__ pb, float* __restrict__ out)
{
    __shared__ __align__(16) ushort_t Ks[2][64 * 64];   // [k][d], swizzled by k&7
    __shared__ __align__(16) ushort_t Vt[2][64 * 64];   // [d][k], swizzled by d&7
    __shared__ float pbL[2048];                          // pb[h][rel], rel=i-k>=0

    const int t = threadIdx.x, w = t >> 6, ln = t & 15, qd = (t >> 4) & 3;

    // block-id remap: r = CU slot (same bh for all 4 rounds), g = round
    const int id = blockIdx.x;
    const int r_ = id & 255, g_ = id >> 8;
    const int bh = r_ & 31, tq = r_ >> 5;             // tq in 0..7
    const int qt = (g_ == 0) ? (31 - tq)
                 : (g_ == 1) ? (23 - tq)
                 : (g_ == 2) ? (8 + tq) : tq;         // 64-row q-tile index
    const int b = bh >> 4, h = bh & 15, i0 = qt * 64;
    const int r0 = 16 * w;                            // wave's q-row offset

    const ushort_t* Kbh = kbb + (size_t)bh * SS * DD;
    const ushort_t* Vbh = vtb + (size_t)bh * DD * SS;

    // cooperative stage of one 64x64 K tile + one 64x64 Vt tile (4 loads/thr)
    const int srow = t >> 3, scg = t & 7;             // 32 rows x 8 groups
    auto stage = [&](int buf, int kt) {
        const int k0 = kt * 64;
        gl_lds16(&Kbh[(size_t)(k0 + srow) * DD + scg * 8],      &Ks[buf][w * 512]);
        gl_lds16(&Kbh[(size_t)(k0 + 32 + srow) * DD + scg * 8], &Ks[buf][2048 + w * 512]);
        gl_lds16(&Vbh[(size_t)srow * SS + k0 + scg * 8],        &Vt[buf][w * 512]);
        gl_lds16(&Vbh[(size_t)(32 + srow) * SS + k0 + scg * 8], &Vt[buf][2048 + w * 512]);
    };

    {   // pos_bias slice (rel 0..2047); base only 4B-aligned -> scalar loads
        const float* p = pb + h * (2 * SS - 1) + (SS - 1);
        #pragma unroll
        for (int j = 0; j < 8; ++j) pbL[t * 8 + j] = p[t * 8 + j];
    }

    // Q fragments (B-operand of St): q-row = i0 + r0 + ln
    short8 qf[2];
    #pragma unroll
    for (int kh = 0; kh < 2; ++kh)
        qf[kh] = *(const short8*)&qb[((size_t)bh * SS + i0 + r0 + ln) * DD + (((kh * 4 + qd) ^ (ln & 7)) * 8)];

    stage(0, 0);
    __syncthreads();              // one-time full drain: pbL + qf + tile 0

    floatx4 accpv[4], accsv[4];
    #pragma unroll
    for (int ct = 0; ct < 4; ++ct) {
        accpv[ct] = (floatx4){0.f, 0.f, 0.f, 0.f};
        accsv[ct] = (floatx4){0.f, 0.f, 0.f, 0.f};
    }
    float psum0 = 0.f, psum1 = 0.f;

    for (int kt = 0; kt <= qt; ++kt) {
        const int k0 = kt * 64;
        const bool diag = (kt == qt);                 // block-uniform

        if (!diag) {
            stage((kt + 1) & 1, kt + 1);              // next tile in flight
            asm volatile("s_waitcnt vmcnt(4)" ::: "memory");   // cur tile done
        } else {
            asm volatile("s_waitcnt vmcnt(0)" ::: "memory");
        }
        __builtin_amdgcn_s_barrier();                 // everyone's cur tile done

        const ushort_t* KsC = Ks[kt & 1];
        const ushort_t* VtC = Vt[kt & 1];

        // St = K·Q^T: A = K rows (m=k), B = Q rows (n=q). 4 m-tiles x 2 kh.
        floatx4 aq[4];
        #pragma unroll
        for (int mt = 0; mt < 4; ++mt) aq[mt] = (floatx4){0.f, 0.f, 0.f, 0.f};
        __builtin_amdgcn_s_setprio(1);
        #pragma unroll
        for (int kh = 0; kh < 2; ++kh) {
            const int sw = ((kh * 4 + qd) ^ (ln & 7)) * 8;
            #pragma unroll
            for (int mt = 0; mt < 4; ++mt) {
                short8 af = *(const short8*)&KsC[(mt * 16 + ln) * 64 + sw];
                aq[mt] = __builtin_amdgcn_mfma_f32_16x16x32_bf16(af, qf[kh], aq[mt], 0, 0, 0);
            }
        }
        __builtin_amdgcn_s_setprio(0);

        // softmax terms in registers; lane holds q = ln, k = k0+mt*16+qd*4+reg
        short4_t pfrag[4];
        if (!diag) {
            const int base0 = i0 - k0 + r0 + ln;      // >= 64: never masked
            #pragma unroll
            for (int mt = 0; mt < 4; ++mt) {
                const int base = base0 - mt * 16 - qd * 4;
                const float v0 = aq[mt][0] * 0.125f + pbL[base];
                const float v1 = aq[mt][1] * 0.125f + pbL[base - 1];
                const float v2 = aq[mt][2] * 0.125f + pbL[base - 2];
                const float v3 = aq[mt][3] * 0.125f + pbL[base - 3];
                psum0 += __expf(v0) + __expf(v2);
                psum1 += __expf(v1) + __expf(v3);
                pfrag[mt] = pack_bf16x4(v0, v1, v2, v3);
            }
        } else {
            #pragma unroll
            for (int mt = 0; mt < 4; ++mt) {
                const int base = r0 + ln - mt * 16 - qd * 4;   // i0-k0 == 0
                float vv[4];
                #pragma unroll
                for (int reg = 0; reg < 4; ++reg) {
                    const int rel = base - reg;
                    const bool ok = rel >= 0;
                    const float val = aq[mt][reg] * 0.125f + pbL[ok ? rel : 0];
                    vv[reg] = ok ? val : 0.f;
                    psum0 += ok ? __expf(val) : 0.f;
                }
                pfrag[mt] = pack_bf16x4(vv[0], vv[1], vv[2], vv[3]);
            }
        }

        // PV (and U·V for Sv on the diagonal tile)
        const int iloc = r0 + ln;
        __builtin_amdgcn_s_setprio(1);
        #pragma unroll
        for (int kk = 0; kk < 4; ++kk) {
            short4_t uf;
            if (diag) {
                #pragma unroll
                for (int j = 0; j < 4; ++j)
                    uf[j] = (kk * 16 + qd * 4 + j > iloc) ? (short)0x3F80 : (short)0;
            }
            #pragma unroll
            for (int ct = 0; ct < 4; ++ct) {
                const int off = (ct * 16 + ln) * 64 + (((kk * 2 + (qd >> 1)) ^ (ln & 7)) * 8 + (qd & 1) * 4);
                short4_t bfr = *(const short4_t*)&VtC[off];
                accpv[ct] = __builtin_amdgcn_mfma_f32_16x16x16bf16_1k(pfrag[kk], bfr, accpv[ct], 0, 0, 0);
                if (diag)
                    accsv[ct] = __builtin_amdgcn_mfma_f32_16x16x16bf16_1k(uf, bfr, accsv[ct], 0, 0, 0);
            }
        }
        __builtin_amdgcn_s_setprio(0);

        if (!diag)
            __builtin_amdgcn_s_barrier();             // all reads of cur done
    }

    // row-sum of exp over k: reduce across the 4 quads (same q = ln)
    float p = psum0 + psum1;
    p += __shfl_xor(p, 16, 64);
    p += __shfl_xor(p, 32, 64);
    const float lseq = __logf(p);            // lse for q-row = ln
    float lseR[4];
    #pragma unroll
    for (int reg = 0; reg < 4; ++reg)
        lseR[reg] = __shfl(lseq, qd * 4 + reg, 64);   // lse for C-layout row

    // Tot[d] and beyond-chunk tail[d]: direct reads of the suffix table
    const int cmin = qt + 1;
    float tot[4], tail[4];
    #pragma unroll
    for (int ct = 0; ct < 4; ++ct) {
        const int d = ct * 16 + ln;
        tot[ct]  = segsuf[((size_t)bh * 33) * 64 + d];
        tail[ct] = segsuf[((size_t)bh * 33 + cmin) * 64 + d];
    }

    #pragma unroll
    for (int ct = 0; ct < 4; ++ct) {
        const int d = ct * 16 + ln;
        #pragma unroll
        for (int reg = 0; reg < 4; ++reg) {
            const int ig = i0 + r0 + qd * 4 + reg;
            const float o = accpv[ct][reg] - lseR[reg] * tot[ct]
                          - 1e9f * (accsv[ct][reg] + tail[ct]);
            out[((size_t)(b * SS + ig)) * EE + h * DD + d] = o;
        }
    }
}

// ---------------------------------------------------------------------------
extern "C" void kernel_launch(void* const* d_in, const int* in_sizes, int n_in,
                              void* d_out, int out_size, void* d_ws, size_t ws_size,
                              hipStream_t stream)
{
    const float* query = (const float*)d_in[0];
    const float* key_  = (const float*)d_in[1];
    const float* value = (const float*)d_in[2];
    const float* Wq = (const float*)d_in[3];
    const float* bq = (const float*)d_in[4];
    const float* Wk = (const float*)d_in[5];
    const float* bk = (const float*)d_in[6];
    const float* Wv = (const float*)d_in[7];
    const float* bv = (const float*)d_in[8];
    const float* pb = (const float*)d_in[9];
    float* out = (float*)d_out;

    float* ws = (float*)d_ws;
    const size_t SZ = (size_t)BB * SS * EE;          // 4M elements
    float* segsuf = ws;                               // 32 bh x 33 c x 64 d
    ushort_t* us  = (ushort_t*)(segsuf + (size_t)BB * HH * 33 * DD);
    ushort_t* qbp = us;                               // bf16 q  [bh][s][d] swz
    ushort_t* kbp = qbp + SZ;                         // bf16 k  [bh][s][d] swz
    ushort_t* vtp = kbp + SZ;                         // bf16 vt [bh][d][s] swz
    ushort_t* Xbf = vtp + SZ;                         // 3 x (B*S x E)
    ushort_t* Wbf = Xbf + 3 * SZ;                     // 3 x (E x E)

    const int ngroups = (3 * BB * SS + 3 * EE) * (EE / 8);
    repack_all<<<ngroups / 256, 256, 0, stream>>>(query, key_, value, Wq, Wk, Wv, Xbf, Wbf);

    proj_kernel<<<dim3(BB * SS / 128, EE / 128, 3), 256, 0, stream>>>(
        Xbf, Wbf, bq, bk, bv, qbp, kbp, vtp);

    scan_chunks<<<dim3(8, BB * HH), 256, 0, stream>>>(vtp, segsuf);

    attn_kernel<<<BB * HH * (SS / 64), 256, 0, stream>>>(
        qbp, kbp, vtp, segsuf, pb, out);
}

// Round 7
// 223.098 us; speedup vs baseline: 1.1718x; 1.0096x over previous
//
#include <hip/hip_runtime.h>
#include <math.h>

constexpr int BB = 2;
constexpr int SS = 2048;
constexpr int EE = 1024;
constexpr int HH = 16;
constexpr int DD = 64;

typedef short short8 __attribute__((ext_vector_type(8)));
typedef short short4_t __attribute__((ext_vector_type(4)));
typedef float floatx4 __attribute__((ext_vector_type(4)));
typedef unsigned short ushort_t;

__device__ __forceinline__ ushort_t f2bf(float f) {
    unsigned int u = __float_as_uint(f);
    u += 0x7fffu + ((u >> 16) & 1u);   // RNE
    return (ushort_t)(u >> 16);
}
__device__ __forceinline__ float bf2f(short s) {
    return __uint_as_float(((unsigned)(ushort_t)s) << 16);
}

// RNE f32x4 -> bf16x4 via v_cvt_pk_bf16_f32 (bit-identical to f2bf)
__device__ __forceinline__ short4_t pack_bf16x4(float a, float b, float c, float d) {
    union { unsigned u[2]; short4_t s; } r;
    asm("v_cvt_pk_bf16_f32 %0, %1, %2" : "=v"(r.u[0]) : "v"(a), "v"(b));
    asm("v_cvt_pk_bf16_f32 %0, %1, %2" : "=v"(r.u[1]) : "v"(c), "v"(d));
    return r.s;
}

// async global->LDS, 16 B per lane; LDS dest = wave-uniform base + lane*16
__device__ __forceinline__ void gl_lds16(const void* g, void* l) {
    __builtin_amdgcn_global_load_lds(
        (const __attribute__((address_space(1))) void*)g,
        (__attribute__((address_space(3))) void*)l, 16, 0, 0);
}

// ---------------------------------------------------------------------------
// fp32 -> bf16 repack with XOR-group swizzle (phys group = g ^ (row&7) within
// each 64-col block). All 3 X inputs and all 3 W matrices in one grid.
// [verbatim from R10 — passed]
// ---------------------------------------------------------------------------
__global__ __launch_bounds__(256) void repack_all(
    const float* __restrict__ x0, const float* __restrict__ x1, const float* __restrict__ x2,
    const float* __restrict__ w0, const float* __restrict__ w1, const float* __restrict__ w2,
    ushort_t* __restrict__ Xbf, ushort_t* __restrict__ Wbf)
{
    const int idx = blockIdx.x * 256 + threadIdx.x;   // group-of-8 id
    const int row = idx >> 7;                          // 128 groups per row
    const int gir = idx & 127;
    const float* src;
    ushort_t* dst;
    int r;
    if (row < 3 * BB * SS) {
        const int z = row >> 12; r = row & (BB * SS - 1);
        src = (z == 0) ? x0 : (z == 1) ? x1 : x2;
        dst = Xbf + (size_t)z * BB * SS * EE;
    } else {
        const int rw = row - 3 * BB * SS;
        const int z = rw >> 10; r = rw & (EE - 1);
        src = (z == 0) ? w0 : (z == 1) ? w1 : w2;
        dst = Wbf + (size_t)z * EE * EE;
    }
    const int blk = gir >> 3, g = gir & 7;
    const int gp = g ^ (r & 7);
    const float* sp = src + (size_t)r * EE + gir * 8;
    float4 a = *(const float4*)sp;
    float4 b = *(const float4*)(sp + 4);
    union { unsigned u[4]; short8 s; } o;
    asm("v_cvt_pk_bf16_f32 %0, %1, %2" : "=v"(o.u[0]) : "v"(a.x), "v"(a.y));
    asm("v_cvt_pk_bf16_f32 %0, %1, %2" : "=v"(o.u[1]) : "v"(a.z), "v"(a.w));
    asm("v_cvt_pk_bf16_f32 %0, %1, %2" : "=v"(o.u[2]) : "v"(b.x), "v"(b.y));
    asm("v_cvt_pk_bf16_f32 %0, %1, %2" : "=v"(o.u[3]) : "v"(b.z), "v"(b.w));
    *(short8*)&dst[(size_t)r * EE + blk * 64 + gp * 8] = o.s;
}

// ---------------------------------------------------------------------------
// bf16 projection GEMM: 128x128 tile, BK=64, global_load_lds staging.
// z=0/1: q/k -> [bh][s][d] bf16 swizzled;  z=2: vt -> [bh][d][s] bf16 swizzled
// [R10 structure; ONLY change: vt write adds the half-swap swizzle
//  slow ^ (((d>>3)&1)<<2) — paired with the attn V-read change (rule #21)]
// ---------------------------------------------------------------------------
__global__ __launch_bounds__(256) void proj_kernel(
    const ushort_t* __restrict__ Xall, const ushort_t* __restrict__ Wall,
    const float* __restrict__ bq, const float* __restrict__ bk, const float* __restrict__ bv,
    ushort_t* __restrict__ qb, ushort_t* __restrict__ kbb, ushort_t* __restrict__ vtb)
{
    __shared__ __align__(16) ushort_t Xs[128 * 64];
    __shared__ __align__(16) ushort_t Ws[128 * 64];

    const int z = blockIdx.z;
    const ushort_t* X = Xall + (size_t)z * BB * SS * EE;
    const ushort_t* W = Wall + (size_t)z * EE * EE;
    const float* bias = (z == 0) ? bq : (z == 1) ? bk : bv;

    const int t = threadIdx.x, w = t >> 6, l = t & 63, ln = t & 15, qd = (t >> 4) & 3;
    const int row0 = blockIdx.x * 128;
    const int col0 = blockIdx.y * 128;
    const int wzm = (w & 1) * 64, wzn = (w >> 1) * 64;

    floatx4 acc[4][4];
    #pragma unroll
    for (int i = 0; i < 4; ++i)
        #pragma unroll
        for (int j = 0; j < 4; ++j)
            acc[i][j] = (floatx4){0.f, 0.f, 0.f, 0.f};

    for (int k0 = 0; k0 < EE; k0 += 64) {
        __syncthreads();
        #pragma unroll
        for (int j = 0; j < 4; ++j) {
            const int c = w * 4 + j;
            const int r = c * 8 + (l >> 3);
            gl_lds16(&X[(size_t)(row0 + r) * EE + k0 + (l & 7) * 8], &Xs[c * 512]);
            gl_lds16(&W[(size_t)(col0 + r) * EE + k0 + (l & 7) * 8], &Ws[c * 512]);
        }
        __syncthreads();

        const ushort_t* Am = (z < 2) ? Ws : Xs;
        const ushort_t* Bn = (z < 2) ? Xs : Ws;
        #pragma unroll
        for (int kh = 0; kh < 2; ++kh) {
            const int sw = ((kh * 4 + qd) ^ (ln & 7)) * 8;
            short8 af[4], bfr[4];
            #pragma unroll
            for (int mi = 0; mi < 4; ++mi)
                af[mi] = *(const short8*)&Am[(wzm + mi * 16 + ln) * 64 + sw];
            #pragma unroll
            for (int ni = 0; ni < 4; ++ni)
                bfr[ni] = *(const short8*)&Bn[(wzn + ni * 16 + ln) * 64 + sw];
            #pragma unroll
            for (int mi = 0; mi < 4; ++mi)
                #pragma unroll
                for (int ni = 0; ni < 4; ++ni)
                    acc[mi][ni] = __builtin_amdgcn_mfma_f32_16x16x32_bf16(af[mi], bfr[ni], acc[mi][ni], 0, 0, 0);
        }
    }

    if (z < 2) {
        ushort_t* dst = z ? kbb : qb;
        #pragma unroll
        for (int mi = 0; mi < 4; ++mi) {
            const int o0 = col0 + wzm + mi * 16 + qd * 4;
            const float4 b4 = *(const float4*)&bias[o0];
            const int h = o0 >> 6, d0 = o0 & 63;
            const int g = d0 >> 3, dlow = d0 & 7;
            #pragma unroll
            for (int ni = 0; ni < 4; ++ni) {
                const int s = row0 + wzn + ni * 16 + ln;
                const int b = s >> 11, sr = s & (SS - 1);
                const int gp = g ^ (sr & 7);
                short4_t pk = pack_bf16x4(acc[mi][ni][0] + b4.x, acc[mi][ni][1] + b4.y,
                                          acc[mi][ni][2] + b4.z, acc[mi][ni][3] + b4.w);
                *(short4_t*)&dst[((size_t)((b * HH + h) * SS) + sr) * DD + gp * 8 + dlow] = pk;
            }
        }
    } else {
        #pragma unroll
        for (int mi = 0; mi < 4; ++mi) {
            const int s0 = row0 + wzm + mi * 16 + qd * 4;
            const int b = s0 >> 11, sr0 = s0 & (SS - 1);
            const int sg = (sr0 >> 3) & 7, slow = sr0 & 7;   // slow in {0,4}
            #pragma unroll
            for (int ni = 0; ni < 4; ++ni) {
                const int o = col0 + wzn + ni * 16 + ln;
                const int h = o >> 6, d = o & 63;
                const float bvv = bias[o];
                const int gp2 = sg ^ (d & 7);
                const int hsw = ((d >> 3) & 1) << 2;         // half-swap key
                short4_t pk = pack_bf16x4(acc[mi][ni][0] + bvv, acc[mi][ni][1] + bvv,
                                          acc[mi][ni][2] + bvv, acc[mi][ni][3] + bvv);
                *(short4_t*)&vtb[((size_t)((b * HH + h) * DD) + d) * SS + (sr0 & ~63) + gp2 * 8 + (slow ^ hsw)] = pk;
            }
        }
    }
}

// ---------------------------------------------------------------------------
// 64-s chunk SUFFIX sums of V from bf16 vt[bh][d][s].
// Invariant to BOTH vt swizzles (group XOR and half-swap permute only
// within a 64-chunk of the SAME d row; chunk sums unchanged).  [verbatim]
// ---------------------------------------------------------------------------
__global__ __launch_bounds__(256) void scan_chunks(
    const ushort_t* __restrict__ vtb, float* __restrict__ segsuf)
{
    const int t = threadIdx.x;
    const int d = blockIdx.x * 8 + (t >> 5);
    const int ch = t & 31;
    const int bh = blockIdx.y;
    const ushort_t* src = vtb + ((size_t)(bh * DD + d)) * SS + ch * 64;
    float s = 0.f;
    #pragma unroll
    for (int i = 0; i < 8; ++i) {
        short8 v = *(const short8*)&src[i * 8];
        #pragma unroll
        for (int j = 0; j < 8; ++j) s += bf2f(v[j]);
    }
    #pragma unroll
    for (int delta = 1; delta < 32; delta <<= 1) {
        const float v = __shfl_down(s, delta, 32);
        if (ch + delta < 32) s += v;
    }
    segsuf[((size_t)bh * 33 + ch) * 64 + d] = s;
    if (ch == 31) segsuf[((size_t)bh * 33 + 32) * 64 + d] = 0.f;
}

// ---------------------------------------------------------------------------
// MFMA causal attention, log-softmax decomposition, P kept in registers.
// R12 == R11 resubmitted verbatim (R11's bench was an infra failure:
// container acquisition died twice; no kernel signal). Change vs R10 (the
// last measured kernel, 47.4us): ONE delta — the V-read half-swap swizzle.
// Quarter-wave bank model (validated by the K-path being conflict-free):
// R10's V ds_read_b64 put all 16 lanes of a quarter-wave in the SAME 8B
// half -> 8 slots/16 banks, 2 addrs per bank = the 4.39M conflict cycles.
// Half-swap keyed on bit 3 of d gives lanes ln and ln+8 opposite halves ->
// 16 lanes on 16 distinct 8B slots = all 32 banks exactly once = free.
// Paired with proj's vt write change (rule #21: both sides or neither).
// ---------------------------------------------------------------------------
__global__ __launch_bounds__(256, 4) void attn_kernel(
    const ushort_t* __restrict__ qb, const ushort_t* __restrict__ kbb,
    const ushort_t* __restrict__ vtb, const float* __restrict__ segsuf,
    const float* __restrict__ pb, float* __restrict__ out)
{
    __shared__ __align__(16) ushort_t Ks[2][64 * 64];   // [k][d], swizzled by k&7
    __shared__ __align__(16) ushort_t Vt[2][64 * 64];   // [d][k], swz by d&7 + half-swap
    __shared__ float pbL[2048];                          // pb[h][rel], rel=i-k>=0

    const int t = threadIdx.x, w = t >> 6, ln = t & 15, qd = (t >> 4) & 3;

    // block-id remap: r = CU slot (same bh for all 4 rounds), g = round
    const int id = blockIdx.x;
    const int r_ = id & 255, g_ = id >> 8;
    const int bh = r_ & 31, tq = r_ >> 5;             // tq in 0..7
    const int qt = (g_ == 0) ? (31 - tq)
                 : (g_ == 1) ? (23 - tq)
                 : (g_ == 2) ? (8 + tq) : tq;         // 64-row q-tile index
    const int b = bh >> 4, h = bh & 15, i0 = qt * 64;
    const int r0 = 16 * w;                            // wave's q-row offset

    const ushort_t* Kbh = kbb + (size_t)bh * SS * DD;
    const ushort_t* Vbh = vtb + (size_t)bh * DD * SS;

    // cooperative stage of one 64x64 K tile + one 64x64 Vt tile (4 loads/thr)
    const int srow = t >> 3, scg = t & 7;             // 32 rows x 8 groups
    auto stage = [&](int buf, int kt) {
        const int k0 = kt * 64;
        gl_lds16(&Kbh[(size_t)(k0 + srow) * DD + scg * 8],      &Ks[buf][w * 512]);
        gl_lds16(&Kbh[(size_t)(k0 + 32 + srow) * DD + scg * 8], &Ks[buf][2048 + w * 512]);
        gl_lds16(&Vbh[(size_t)srow * SS + k0 + scg * 8],        &Vt[buf][w * 512]);
        gl_lds16(&Vbh[(size_t)(32 + srow) * SS + k0 + scg * 8], &Vt[buf][2048 + w * 512]);
    };

    {   // pos_bias slice (rel 0..2047); base only 4B-aligned -> scalar loads
        const float* p = pb + h * (2 * SS - 1) + (SS - 1);
        #pragma unroll
        for (int j = 0; j < 8; ++j) pbL[t * 8 + j] = p[t * 8 + j];
    }

    // Q fragments (B-operand of St): q-row = i0 + r0 + ln
    short8 qf[2];
    #pragma unroll
    for (int kh = 0; kh < 2; ++kh)
        qf[kh] = *(const short8*)&qb[((size_t)bh * SS + i0 + r0 + ln) * DD + (((kh * 4 + qd) ^ (ln & 7)) * 8)];

    stage(0, 0);
    __syncthreads();              // one-time full drain: pbL + qf + tile 0

    floatx4 accpv[4], accsv[4];
    #pragma unroll
    for (int ct = 0; ct < 4; ++ct) {
        accpv[ct] = (floatx4){0.f, 0.f, 0.f, 0.f};
        accsv[ct] = (floatx4){0.f, 0.f, 0.f, 0.f};
    }
    float psum0 = 0.f, psum1 = 0.f;

    // V sub-offset with half-swap: ((qd&1) ^ ((ln>>3)&1)) * 4
    const int vhalf = ((qd & 1) ^ ((ln >> 3) & 1)) * 4;

    for (int kt = 0; kt <= qt; ++kt) {
        const int k0 = kt * 64;
        const bool diag = (kt == qt);                 // block-uniform

        if (!diag) {
            stage((kt + 1) & 1, kt + 1);              // next tile in flight
            asm volatile("s_waitcnt vmcnt(4)" ::: "memory");   // cur tile done
        } else {
            asm volatile("s_waitcnt vmcnt(0)" ::: "memory");
        }
        __builtin_amdgcn_s_barrier();                 // everyone's cur tile done

        const ushort_t* KsC = Ks[kt & 1];
        const ushort_t* VtC = Vt[kt & 1];

        // St = K·Q^T: A = K rows (m=k), B = Q rows (n=q). 4 m-tiles x 2 kh.
        floatx4 aq[4];
        #pragma unroll
        for (int mt = 0; mt < 4; ++mt) aq[mt] = (floatx4){0.f, 0.f, 0.f, 0.f};
        __builtin_amdgcn_s_setprio(1);
        #pragma unroll
        for (int kh = 0; kh < 2; ++kh) {
            const int sw = ((kh * 4 + qd) ^ (ln & 7)) * 8;
            #pragma unroll
            for (int mt = 0; mt < 4; ++mt) {
                short8 af = *(const short8*)&KsC[(mt * 16 + ln) * 64 + sw];
                aq[mt] = __builtin_amdgcn_mfma_f32_16x16x32_bf16(af, qf[kh], aq[mt], 0, 0, 0);
            }
        }
        __builtin_amdgcn_s_setprio(0);

        // softmax terms in registers; lane holds q = ln, k = k0+mt*16+qd*4+reg
        short4_t pfrag[4];
        if (!diag) {
            const int base0 = i0 - k0 + r0 + ln;      // >= 64: never masked
            #pragma unroll
            for (int mt = 0; mt < 4; ++mt) {
                const int base = base0 - mt * 16 - qd * 4;
                const float v0 = aq[mt][0] * 0.125f + pbL[base];
                const float v1 = aq[mt][1] * 0.125f + pbL[base - 1];
                const float v2 = aq[mt][2] * 0.125f + pbL[base - 2];
                const float v3 = aq[mt][3] * 0.125f + pbL[base - 3];
                psum0 += __expf(v0) + __expf(v2);
                psum1 += __expf(v1) + __expf(v3);
                pfrag[mt] = pack_bf16x4(v0, v1, v2, v3);
            }
        } else {
            #pragma unroll
            for (int mt = 0; mt < 4; ++mt) {
                const int base = r0 + ln - mt * 16 - qd * 4;   // i0-k0 == 0
                float vv[4];
                #pragma unroll
                for (int reg = 0; reg < 4; ++reg) {
                    const int rel = base - reg;
                    const bool ok = rel >= 0;
                    const float val = aq[mt][reg] * 0.125f + pbL[ok ? rel : 0];
                    vv[reg] = ok ? val : 0.f;
                    psum0 += ok ? __expf(val) : 0.f;
                }
                pfrag[mt] = pack_bf16x4(vv[0], vv[1], vv[2], vv[3]);
            }
        }

        // PV (and U·V for Sv on the diagonal tile)
        const int iloc = r0 + ln;
        __builtin_amdgcn_s_setprio(1);
        #pragma unroll
        for (int kk = 0; kk < 4; ++kk) {
            short4_t uf;
            if (diag) {
                #pragma unroll
                for (int j = 0; j < 4; ++j)
                    uf[j] = (kk * 16 + qd * 4 + j > iloc) ? (short)0x3F80 : (short)0;
            }
            #pragma unroll
            for (int ct = 0; ct < 4; ++ct) {
                const int off = (ct * 16 + ln) * 64 + (((kk * 2 + (qd >> 1)) ^ (ln & 7)) * 8 + vhalf);
                short4_t bfr = *(const short4_t*)&VtC[off];
                accpv[ct] = __builtin_amdgcn_mfma_f32_16x16x16bf16_1k(pfrag[kk], bfr, accpv[ct], 0, 0, 0);
                if (diag)
                    accsv[ct] = __builtin_amdgcn_mfma_f32_16x16x16bf16_1k(uf, bfr, accsv[ct], 0, 0, 0);
            }
        }
        __builtin_amdgcn_s_setprio(0);

        if (!diag)
            __builtin_amdgcn_s_barrier();             // all reads of cur done
    }

    // row-sum of exp over k: reduce across the 4 quads (same q = ln)
    float p = psum0 + psum1;
    p += __shfl_xor(p, 16, 64);
    p += __shfl_xor(p, 32, 64);
    const float lseq = __logf(p);            // lse for q-row = ln
    float lseR[4];
    #pragma unroll
    for (int reg = 0; reg < 4; ++reg)
        lseR[reg] = __shfl(lseq, qd * 4 + reg, 64);   // lse for C-layout row

    // Tot[d] and beyond-chunk tail[d]: direct reads of the suffix table
    const int cmin = qt + 1;
    float tot[4], tail[4];
    #pragma unroll
    for (int ct = 0; ct < 4; ++ct) {
        const int d = ct * 16 + ln;
        tot[ct]  = segsuf[((size_t)bh * 33) * 64 + d];
        tail[ct] = segsuf[((size_t)bh * 33 + cmin) * 64 + d];
    }

    #pragma unroll
    for (int ct = 0; ct < 4; ++ct) {
        const int d = ct * 16 + ln;
        #pragma unroll
        for (int reg = 0; reg < 4; ++reg) {
            const int ig = i0 + r0 + qd * 4 + reg;
            const float o = accpv[ct][reg] - lseR[reg] * tot[ct]
                          - 1e9f * (accsv[ct][reg] + tail[ct]);
            out[((size_t)(b * SS + ig)) * EE + h * DD + d] = o;
        }
    }
}

// ---------------------------------------------------------------------------
extern "C" void kernel_launch(void* const* d_in, const int* in_sizes, int n_in,
                              void* d_out, int out_size, void* d_ws, size_t ws_size,
                              hipStream_t stream)
{
    const float* query = (const float*)d_in[0];
    const float* key_  = (const float*)d_in[1];
    const float* value = (const float*)d_in[2];
    const float* Wq = (const float*)d_in[3];
    const float* bq = (const float*)d_in[4];
    const float* Wk = (const float*)d_in[5];
    const float* bk = (const float*)d_in[6];
    const float* Wv = (const float*)d_in[7];
    const float* bv = (const float*)d_in[8];
    const float* pb = (const float*)d_in[9];
    float* out = (float*)d_out;

    float* ws = (float*)d_ws;
    const size_t SZ = (size_t)BB * SS * EE;          // 4M elements
    float* segsuf = ws;                               // 32 bh x 33 c x 64 d
    ushort_t* us  = (ushort_t*)(segsuf + (size_t)BB * HH * 33 * DD);
    ushort_t* qbp = us;                               // bf16 q  [bh][s][d] swz
    ushort_t* kbp = qbp + SZ;                         // bf16 k  [bh][s][d] swz
    ushort_t* vtp = kbp + SZ;                         // bf16 vt [bh][d][s] swz
    ushort_t* Xbf = vtp + SZ;                         // 3 x (B*S x E)
    ushort_t* Wbf = Xbf + 3 * SZ;                     // 3 x (E x E)

    const int ngroups = (3 * BB * SS + 3 * EE) * (EE / 8);
    repack_all<<<ngroups / 256, 256, 0, stream>>>(query, key_, value, Wq, Wk, Wv, Xbf, Wbf);

    proj_kernel<<<dim3(BB * SS / 128, EE / 128, 3), 256, 0, stream>>>(
        Xbf, Wbf, bq, bk, bv, qbp, kbp, vtp);

    scan_chunks<<<dim3(8, BB * HH), 256, 0, stream>>>(vtp, segsuf);

    attn_kernel<<<BB * HH * (SS / 64), 256, 0, stream>>>(
        qbp, kbp, vtp, segsuf, pb, out);
}